// Round 1
// baseline (736.365 us; speedup 1.0000x reference)
//
#include <hip/hip_runtime.h>
#include <math.h>

#define BB 8
#define LL 2048
#define DD 512
#define HH 8
#define DHH 64
#define KD 8
#define MM (BB*LL)   // 16384

// ---------------- GEMM: C = X @ W^T + bias ----------------
// X: [M,512] row-major, W: [512,512] row-major: C[m,n] = sum_k X[m,k]*W[n,k] + bias[n]
// mode 0: C[m*512 + n]                              (standard [B,L,D])
// mode 1: C[(b*512 + n)*2048 + l]                   (q/k layout [B,H,DH,L], n = h*64+dh)
// mode 2: C[b*1048576 + (n>>6)*131072 + l*64 + (n&63)]  (v layout [B,H,L,DH])
__global__ __launch_bounds__(256) void gemm_bias(const float* __restrict__ X,
                                                 const float* __restrict__ W,
                                                 const float* __restrict__ bias,
                                                 float* __restrict__ C,
                                                 int mode) {
    __shared__ float As[16][68];   // k-major, padded: row stride 68 floats (16B aligned)
    __shared__ float Bs[16][68];

    const int t   = threadIdx.x;
    const int tx  = t & 15;
    const int ty  = t >> 4;
    const int tx4 = tx * 4;
    const int ty4 = ty * 4;
    const int m0  = blockIdx.y * 64;
    const int n0  = blockIdx.x * 64;

    const int lrow = t >> 2;        // 0..63
    const int lkq  = (t & 3) * 4;   // 0,4,8,12

    const float* Xp = X + (size_t)(m0 + lrow) * 512 + lkq;
    const float* Wp = W + (size_t)(n0 + lrow) * 512 + lkq;

    float acc[4][4] = {};

    float4 a_reg = *(const float4*)(Xp);
    float4 b_reg = *(const float4*)(Wp);

    for (int k0 = 0; k0 < 512; k0 += 16) {
        __syncthreads();   // previous iteration's compute done before overwrite
        As[lkq + 0][lrow] = a_reg.x;
        As[lkq + 1][lrow] = a_reg.y;
        As[lkq + 2][lrow] = a_reg.z;
        As[lkq + 3][lrow] = a_reg.w;
        Bs[lkq + 0][lrow] = b_reg.x;
        Bs[lkq + 1][lrow] = b_reg.y;
        Bs[lkq + 2][lrow] = b_reg.z;
        Bs[lkq + 3][lrow] = b_reg.w;
        __syncthreads();

        if (k0 + 16 < 512) {   // prefetch next K-tile while computing
            a_reg = *(const float4*)(Xp + k0 + 16);
            b_reg = *(const float4*)(Wp + k0 + 16);
        }

#pragma unroll
        for (int kk = 0; kk < 16; kk++) {
            const float4 a  = *reinterpret_cast<const float4*>(&As[kk][ty4]);
            const float4 bq = *reinterpret_cast<const float4*>(&Bs[kk][tx4]);
            const float av[4] = {a.x, a.y, a.z, a.w};
            const float bv[4] = {bq.x, bq.y, bq.z, bq.w};
#pragma unroll
            for (int i = 0; i < 4; i++)
#pragma unroll
                for (int j = 0; j < 4; j++)
                    acc[i][j] = fmaf(av[i], bv[j], acc[i][j]);
        }
    }

#pragma unroll
    for (int i = 0; i < 4; i++) {
        const int m = m0 + ty4 + i;
        const int b_idx = m >> 11;
        const int l     = m & 2047;
#pragma unroll
        for (int j = 0; j < 4; j++) {
            const int n = n0 + tx4 + j;
            const float val = acc[i][j] + bias[n];
            size_t addr;
            if (mode == 0)      addr = (size_t)m * 512 + n;
            else if (mode == 1) addr = ((size_t)(b_idx * 512 + n)) * 2048 + l;
            else                addr = (size_t)b_idx * 1048576 + (size_t)(n >> 6) * 131072
                                       + (size_t)l * 64 + (n & 63);
            C[addr] = val;
        }
    }
}

// ---------------- in-LDS radix-2 FFT, N=2048, 256 threads ----------------
__device__ inline void fft2048(float2* Z, int tid, float sign) {
    // bit-reverse permutation (11 bits)
    float2 tmp[8];
    int dst[8];
#pragma unroll
    for (int s = 0; s < 8; s++) {
        const int i = tid + s * 256;
        dst[s] = (int)(__brev((unsigned)i) >> 21);
        tmp[s] = Z[i];
    }
    __syncthreads();
#pragma unroll
    for (int s = 0; s < 8; s++) Z[dst[s]] = tmp[s];
    __syncthreads();

    for (int st = 0; st < 11; st++) {
        const int half = 1 << st;
#pragma unroll
        for (int r = 0; r < 4; r++) {
            const int m   = tid + r * 256;           // 1024 disjoint butterflies
            const int grp = m >> st;
            const int pos = m & (half - 1);
            const int i0  = (grp << (st + 1)) + pos;
            const int i1  = i0 + half;
            const float ang = sign * (float)M_PI * (float)pos / (float)half;
            float sv, cv;
            __sincosf(ang, &sv, &cv);
            const float2 a = Z[i0];
            const float2 b = Z[i1];
            const float tr = b.x * cv - b.y * sv;
            const float ti = b.x * sv + b.y * cv;
            Z[i0] = make_float2(a.x + tr, a.y + ti);
            Z[i1] = make_float2(a.x - tr, a.y - ti);
        }
        __syncthreads();
    }
}

// forward: one block per (b,h,dh) sequence; pack z = q + i*k; accumulate
// spectral product Qf*conj(Kf) over dh into spec[bh][f] (f = 0..1024)
__global__ __launch_bounds__(256) void fft_fwd(const float* __restrict__ qT,
                                               const float* __restrict__ kT,
                                               float* __restrict__ spec) {
    const int seq = blockIdx.x;          // (b*H + h)*64 + dh
    const int tid = threadIdx.x;
    __shared__ float2 Z[2048];

    const float* qp = qT + (size_t)seq * 2048;
    const float* kp = kT + (size_t)seq * 2048;
#pragma unroll
    for (int s = 0; s < 8; s++) {
        const int i = tid + s * 256;
        Z[i] = make_float2(qp[i], kp[i]);
    }
    __syncthreads();
    fft2048(Z, tid, -1.0f);

    const int bh = seq >> 6;
    float* sp = spec + (size_t)bh * 1025 * 2;
    for (int f = tid; f <= 1024; f += 256) {
        const int fm = (2048 - f) & 2047;
        const float2 zf = Z[f];
        const float2 zm = Z[fm];
        const float qr = 0.5f * (zf.x + zm.x);
        const float qi = 0.5f * (zf.y - zm.y);
        const float kr = 0.5f * (zf.y + zm.y);
        const float ki = 0.5f * (zm.x - zf.x);
        float pr = qr * kr + qi * ki;       // Qf * conj(Kf)
        float pi = qi * kr - qr * ki;
        if (f == 0) { pr = 0.0f; pi = 0.0f; }   // mean-subtraction == zero DC bin
        atomicAdd(&sp[f * 2 + 0], pr);
        atomicAdd(&sp[f * 2 + 1], pi);
    }
}

// inverse + top-8: one block per (b,h)
__global__ __launch_bounds__(256) void fft_inv_topk(const float* __restrict__ spec,
                                                    int* __restrict__ delays,
                                                    float* __restrict__ weights) {
    const int bh  = blockIdx.x;   // 0..63
    const int tid = threadIdx.x;
    __shared__ float2 Z[2048];
    __shared__ float  corrS[2048];
    __shared__ float  rv[256];
    __shared__ int    ri[256];
    __shared__ float  vals[KD];
    __shared__ int    inds[KD];

    const float* sp = spec + (size_t)bh * 1025 * 2;
    for (int f = tid; f < 1025; f += 256) {
        const float pr = sp[2 * f];
        const float pi = sp[2 * f + 1];
        Z[f] = make_float2(pr, pi);
        if (f >= 1 && f <= 1023) Z[2048 - f] = make_float2(pr, -pi);
    }
    __syncthreads();
    fft2048(Z, tid, +1.0f);

    const float scale = 1.0f / (2048.0f * 64.0f);   // irfft 1/N and mean over dh
#pragma unroll
    for (int s = 0; s < 8; s++) {
        const int i = tid + s * 256;
        corrS[i] = Z[i].x * scale;
    }
    __syncthreads();

    for (int k = 0; k < KD; k++) {
        float best = -1e30f;
        int   bi   = 1 << 30;
        for (int i = tid; i < 2048; i += 256) {
            const float v = corrS[i];
            if (v > best || (v == best && i < bi)) { best = v; bi = i; }
        }
        rv[tid] = best;
        ri[tid] = bi;
        __syncthreads();
        for (int off = 128; off > 0; off >>= 1) {
            if (tid < off) {
                const float v2 = rv[tid + off];
                const int   i2 = ri[tid + off];
                if (v2 > rv[tid] || (v2 == rv[tid] && i2 < ri[tid])) {
                    rv[tid] = v2; ri[tid] = i2;
                }
            }
            __syncthreads();
        }
        if (tid == 0) {
            vals[k] = rv[0];
            inds[k] = ri[0];
            corrS[ri[0]] = -1e30f;
        }
        __syncthreads();
    }

    if (tid == 0) {
        float sum = 0.0f;
        for (int k = 0; k < KD; k++) sum += vals[k];
        const float inv = 1.0f / (sum + 1e-12f);
        for (int k = 0; k < KD; k++) {
            weights[bh * KD + k] = vals[k] * inv;
            delays[bh * KD + k]  = inds[k];
        }
    }
}

// weighted circular-shift gather: outb[b,l,h*64+dh] = sum_k w_k * v[b,h,(l+d_k)%L,dh]
__global__ __launch_bounds__(256) void gather_ws(const float* __restrict__ v,
                                                 const int* __restrict__ delays,
                                                 const float* __restrict__ weights,
                                                 float* __restrict__ outb) {
    const int g  = blockIdx.x * 256 + threadIdx.x;   // over B*L*D = 8388608
    const int c  = g & 511;
    const int bl = g >> 9;
    const int l  = bl & 2047;
    const int b  = bl >> 11;
    const int h  = c >> 6;
    const int dh = c & 63;
    const int bh = b * 8 + h;

    const float* vb = v + (size_t)bh * 131072;   // [L,64]
    float acc = 0.0f;
#pragma unroll
    for (int k = 0; k < KD; k++) {
        const int   d = delays[bh * KD + k];
        const float w = weights[bh * KD + k];
        const int   p = (l + d) & 2047;
        acc = fmaf(w, vb[p * 64 + dh], acc);
    }
    outb[g] = acc;
}

extern "C" void kernel_launch(void* const* d_in, const int* in_sizes, int n_in,
                              void* d_out, int out_size, void* d_ws, size_t ws_size,
                              hipStream_t stream) {
    const float* x_q  = (const float*)d_in[0];
    const float* x_kv = (const float*)d_in[1];
    const float* Wq   = (const float*)d_in[2];
    const float* bq   = (const float*)d_in[3];
    const float* Wk   = (const float*)d_in[4];
    const float* bk   = (const float*)d_in[5];
    const float* Wv   = (const float*)d_in[6];
    const float* bv   = (const float*)d_in[7];
    const float* Wo   = (const float*)d_in[8];
    const float* bo   = (const float*)d_in[9];
    float* out = (float*)d_out;

    char* ws = (char*)d_ws;
    float* qbuf  = (float*)(ws + 0);            // 33554432 B, [B,H,DH,L]; reused as outb
    float* kbuf  = (float*)(ws + 33554432);     // 33554432 B, [B,H,DH,L]
    float* vbuf  = (float*)(ws + 67108864);     // 33554432 B, [B,H,L,DH]
    float* spec  = (float*)(ws + 100663296);    // 64*1025*2*4 = 524800 B
    int*   dely  = (int*)  (ws + 101188096);    // 2048 B
    float* wgt   = (float*)(ws + 101190144);    // 2048 B

    dim3 blk(256);
    dim3 gg(DD / 64, MM / 64);   // (8, 256)

    // q, k projections into [B,H,DH,L]
    gemm_bias<<<gg, blk, 0, stream>>>(x_q,  Wq, bq, qbuf, 1);
    gemm_bias<<<gg, blk, 0, stream>>>(x_kv, Wk, bk, kbuf, 1);

    // spectral accumulator must start at zero (ws is poisoned before every call)
    hipMemsetAsync(spec, 0, 64 * 1025 * 2 * sizeof(float), stream);

    fft_fwd<<<dim3(BB * HH * DHH), blk, 0, stream>>>(qbuf, kbuf, spec);
    fft_inv_topk<<<dim3(BB * HH), blk, 0, stream>>>(spec, dely, wgt);

    // v projection into [B,H,L,DH]
    gemm_bias<<<gg, blk, 0, stream>>>(x_kv, Wv, bv, vbuf, 2);

    // weighted circular gather -> [B,L,D] (reuse qbuf)
    gather_ws<<<dim3(MM * DD / 256), blk, 0, stream>>>(vbuf, dely, wgt, qbuf);

    // final projection
    gemm_bias<<<gg, blk, 0, stream>>>(qbuf, Wo, bo, out, 0);
}

// Round 2
// 385.751 us; speedup vs baseline: 1.9089x; 1.9089x over previous
//
#include <hip/hip_runtime.h>
#include <math.h>

#define BB 8
#define LL 2048
#define DD 512
#define HH 8
#define DHH 64
#define KD 8
#define MM (BB*LL)   // 16384

typedef _Float16 f16x4 __attribute__((ext_vector_type(4)));
typedef _Float16 f16x8 __attribute__((ext_vector_type(8)));
typedef float    f32x4 __attribute__((ext_vector_type(4)));

// ---------------- MFMA GEMM: C = X @ W^T + bias ----------------
// X: [M,512] fp32 row-major, W: [512,512] fp32 row-major.
// NPROD==1: plain fp16 (1 MFMA product)  — for v / o projections.
// NPROD==3: hi/lo split, lo scaled by 512, correction in acc1 — for q / k
//           (score path needs ~1e-6-grade relative accuracy so top-8 ranks
//            match numpy; plain fp16 would flip ranks).
// mode 0: C[m*512 + n]
// mode 1: C[(b*512 + n)*2048 + l]               (q/k [B,H,DH,L])
// mode 2: C[b*1048576 + h*131072 + l*64 + dh]   (v   [B,H,L,DH])
template<int NPROD>
__global__ __launch_bounds__(256, 2) void gemm_mfma(const float* __restrict__ X,
                                                    const float* __restrict__ W,
                                                    const float* __restrict__ bias,
                                                    float* __restrict__ C,
                                                    int mode) {
    // [128][40] halves per tile: row stride 80 B (16B aligned, odd bank stride)
    __shared__ __align__(16) _Float16 lds[(NPROD == 3) ? 20480 : 10240];
    _Float16* Ah = lds;            // hi tiles
    _Float16* Bh = lds + 5120;
    _Float16* Al = (NPROD == 3) ? lds + 10240 : lds;
    _Float16* Bl = (NPROD == 3) ? lds + 15360 : lds;

    const int t    = threadIdx.x;
    const int m0   = blockIdx.y * 128;
    const int n0   = blockIdx.x * 128;
    const int srow = t >> 3;        // 0..31 (staging row within pass)
    const int scol = (t & 7) * 4;   // k offset 0..28
    const int wave = t >> 6;
    const int lane = t & 63;
    const int wm   = (wave >> 1) * 64;
    const int wn   = (wave & 1) * 64;
    const int lm   = lane & 15;
    const int quad = lane >> 4;     // 0..3

    f32x4 acc0[4][4] = {};
    f32x4 acc1[4][4] = {};

    float4 ar[4], br[4];
#pragma unroll
    for (int p = 0; p < 4; p++) {
        ar[p] = *(const float4*)(X + (size_t)(m0 + p * 32 + srow) * 512 + scol);
        br[p] = *(const float4*)(W + (size_t)(n0 + p * 32 + srow) * 512 + scol);
    }

    for (int k0 = 0; k0 < 512; k0 += 32) {
        __syncthreads();
#pragma unroll
        for (int p = 0; p < 4; p++) {
            const int row = p * 32 + srow;
            const float xa[4] = {ar[p].x, ar[p].y, ar[p].z, ar[p].w};
            const float xb[4] = {br[p].x, br[p].y, br[p].z, br[p].w};
            f16x4 ha, hb, la, lb;
#pragma unroll
            for (int j = 0; j < 4; j++) {
                const _Float16 h1 = (_Float16)xa[j];
                const _Float16 h2 = (_Float16)xb[j];
                ha[j] = h1; hb[j] = h2;
                if (NPROD == 3) {
                    la[j] = (_Float16)((xa[j] - (float)h1) * 512.0f);
                    lb[j] = (_Float16)((xb[j] - (float)h2) * 512.0f);
                }
            }
            *(f16x4*)&Ah[row * 40 + scol] = ha;
            *(f16x4*)&Bh[row * 40 + scol] = hb;
            if (NPROD == 3) {
                *(f16x4*)&Al[row * 40 + scol] = la;
                *(f16x4*)&Bl[row * 40 + scol] = lb;
            }
        }
        __syncthreads();

        if (k0 + 32 < 512) {   // prefetch next K-tile
#pragma unroll
            for (int p = 0; p < 4; p++) {
                ar[p] = *(const float4*)(X + (size_t)(m0 + p * 32 + srow) * 512 + k0 + 32 + scol);
                br[p] = *(const float4*)(W + (size_t)(n0 + p * 32 + srow) * 512 + k0 + 32 + scol);
            }
        }

        f16x8 afh[4], bf[4];
#pragma unroll
        for (int mt = 0; mt < 4; mt++)
            afh[mt] = *(f16x8*)&Ah[(wm + mt * 16 + lm) * 40 + quad * 8];
#pragma unroll
        for (int nt = 0; nt < 4; nt++)
            bf[nt] = *(f16x8*)&Bh[(wn + nt * 16 + lm) * 40 + quad * 8];

#pragma unroll
        for (int mt = 0; mt < 4; mt++)
#pragma unroll
            for (int nt = 0; nt < 4; nt++)
                acc0[mt][nt] = __builtin_amdgcn_mfma_f32_16x16x32_f16(afh[mt], bf[nt], acc0[mt][nt], 0, 0, 0);

        if (NPROD == 3) {
            f16x8 afl[4];
#pragma unroll
            for (int mt = 0; mt < 4; mt++)
                afl[mt] = *(f16x8*)&Al[(wm + mt * 16 + lm) * 40 + quad * 8];
#pragma unroll
            for (int mt = 0; mt < 4; mt++)
#pragma unroll
                for (int nt = 0; nt < 4; nt++)
                    acc1[mt][nt] = __builtin_amdgcn_mfma_f32_16x16x32_f16(afl[mt], bf[nt], acc1[mt][nt], 0, 0, 0);
#pragma unroll
            for (int nt = 0; nt < 4; nt++)
                bf[nt] = *(f16x8*)&Bl[(wn + nt * 16 + lm) * 40 + quad * 8];
#pragma unroll
            for (int mt = 0; mt < 4; mt++)
#pragma unroll
                for (int nt = 0; nt < 4; nt++)
                    acc1[mt][nt] = __builtin_amdgcn_mfma_f32_16x16x32_f16(afh[mt], bf[nt], acc1[mt][nt], 0, 0, 0);
        }
    }

    // epilogue: C/D layout col=lane&15, row=quad*4+reg
#pragma unroll
    for (int mt = 0; mt < 4; mt++) {
#pragma unroll
        for (int nt = 0; nt < 4; nt++) {
            const int n = n0 + wn + nt * 16 + lm;
            const float bv = bias[n];
#pragma unroll
            for (int r = 0; r < 4; r++) {
                const int m = m0 + wm + mt * 16 + quad * 4 + r;
                float val = acc0[mt][nt][r] + bv;
                if (NPROD == 3) val += acc1[mt][nt][r] * (1.0f / 512.0f);
                const int b_idx = m >> 11;
                const int l     = m & 2047;
                size_t addr;
                if (mode == 0)      addr = (size_t)m * 512 + n;
                else if (mode == 1) addr = ((size_t)(b_idx * 512 + n)) * 2048 + l;
                else                addr = (size_t)b_idx * 1048576 + (size_t)(n >> 6) * 131072
                                           + (size_t)l * 64 + (n & 63);
                C[addr] = val;
            }
        }
    }
}

// ---------------- in-LDS radix-2 FFT, N=2048, 256 threads ----------------
// Wt[j] = (cos(2*pi*j/2048), sign*sin(2*pi*j/2048)), j=0..1023
__device__ inline void build_twiddle(float2* Wt, int tid, float sign) {
#pragma unroll
    for (int s = 0; s < 4; s++) {
        const int j = tid + s * 256;
        const float a = 2.0f * (float)M_PI * (float)j / 2048.0f;
        float sv, cv;
        __sincosf(a, &sv, &cv);
        Wt[j] = make_float2(cv, sign * sv);
    }
}

__device__ inline void fft2048(float2* Z, const float2* Wt, int tid) {
    float2 tmp[8];
    int dst[8];
#pragma unroll
    for (int s = 0; s < 8; s++) {
        const int i = tid + s * 256;
        dst[s] = (int)(__brev((unsigned)i) >> 21);
        tmp[s] = Z[i];
    }
    __syncthreads();
#pragma unroll
    for (int s = 0; s < 8; s++) Z[dst[s]] = tmp[s];
    __syncthreads();

    for (int st = 0; st < 11; st++) {
        const int half = 1 << st;
        const int shift = 10 - st;
#pragma unroll
        for (int r = 0; r < 4; r++) {
            const int m   = tid + r * 256;
            const int grp = m >> st;
            const int pos = m & (half - 1);
            const int i0  = (grp << (st + 1)) + pos;
            const int i1  = i0 + half;
            const float2 w = Wt[pos << shift];
            const float2 a = Z[i0];
            const float2 b = Z[i1];
            const float tr = b.x * w.x - b.y * w.y;
            const float ti = b.x * w.y + b.y * w.x;
            Z[i0] = make_float2(a.x + tr, a.y + ti);
            Z[i1] = make_float2(a.x - tr, a.y - ti);
        }
        __syncthreads();
    }
}

// forward: one block per (b,h,dh); pack z = q + i*k; accumulate Qf*conj(Kf)
__global__ __launch_bounds__(256) void fft_fwd(const float* __restrict__ qT,
                                               const float* __restrict__ kT,
                                               float* __restrict__ spec) {
    const int seq = blockIdx.x;
    const int tid = threadIdx.x;
    __shared__ float2 Z[2048];
    __shared__ float2 Wt[1024];

    build_twiddle(Wt, tid, -1.0f);

    const float* qp = qT + (size_t)seq * 2048;
    const float* kp = kT + (size_t)seq * 2048;
#pragma unroll
    for (int s = 0; s < 8; s++) {
        const int i = tid + s * 256;
        Z[i] = make_float2(qp[i], kp[i]);
    }
    __syncthreads();
    fft2048(Z, Wt, tid);

    const int bh = seq >> 6;
    float* sp = spec + (size_t)bh * 1025 * 2;
    for (int f = tid; f <= 1024; f += 256) {
        const int fm = (2048 - f) & 2047;
        const float2 zf = Z[f];
        const float2 zm = Z[fm];
        const float qr = 0.5f * (zf.x + zm.x);
        const float qi = 0.5f * (zf.y - zm.y);
        const float kr = 0.5f * (zf.y + zm.y);
        const float ki = 0.5f * (zm.x - zf.x);
        float pr = qr * kr + qi * ki;
        float pi = qi * kr - qr * ki;
        if (f == 0) { pr = 0.0f; pi = 0.0f; }
        atomicAdd(&sp[f * 2 + 0], pr);
        atomicAdd(&sp[f * 2 + 1], pi);
    }
}

// inverse + top-8: one block per (b,h)
__global__ __launch_bounds__(256) void fft_inv_topk(const float* __restrict__ spec,
                                                    int* __restrict__ delays,
                                                    float* __restrict__ weights) {
    const int bh  = blockIdx.x;
    const int tid = threadIdx.x;
    __shared__ float2 Z[2048];
    __shared__ float2 Wt[1024];
    __shared__ float  corrS[2048];
    __shared__ float  rv[256];
    __shared__ int    ri[256];
    __shared__ float  vals[KD];
    __shared__ int    inds[KD];

    build_twiddle(Wt, tid, +1.0f);

    const float* sp = spec + (size_t)bh * 1025 * 2;
    for (int f = tid; f < 1025; f += 256) {
        const float pr = sp[2 * f];
        const float pi = sp[2 * f + 1];
        Z[f] = make_float2(pr, pi);
        if (f >= 1 && f <= 1023) Z[2048 - f] = make_float2(pr, -pi);
    }
    __syncthreads();
    fft2048(Z, Wt, tid);

    const float scale = 1.0f / (2048.0f * 64.0f);
#pragma unroll
    for (int s = 0; s < 8; s++) {
        const int i = tid + s * 256;
        corrS[i] = Z[i].x * scale;
    }
    __syncthreads();

    for (int k = 0; k < KD; k++) {
        float best = -1e30f;
        int   bi   = 1 << 30;
        for (int i = tid; i < 2048; i += 256) {
            const float v = corrS[i];
            if (v > best || (v == best && i < bi)) { best = v; bi = i; }
        }
        rv[tid] = best;
        ri[tid] = bi;
        __syncthreads();
        for (int off = 128; off > 0; off >>= 1) {
            if (tid < off) {
                const float v2 = rv[tid + off];
                const int   i2 = ri[tid + off];
                if (v2 > rv[tid] || (v2 == rv[tid] && i2 < ri[tid])) {
                    rv[tid] = v2; ri[tid] = i2;
                }
            }
            __syncthreads();
        }
        if (tid == 0) {
            vals[k] = rv[0];
            inds[k] = ri[0];
            corrS[ri[0]] = -1e30f;
        }
        __syncthreads();
    }

    if (tid == 0) {
        float sum = 0.0f;
        for (int k = 0; k < KD; k++) sum += vals[k];
        const float inv = 1.0f / (sum + 1e-12f);
        for (int k = 0; k < KD; k++) {
            weights[bh * KD + k] = vals[k] * inv;
            delays[bh * KD + k]  = inds[k];
        }
    }
}

// weighted circular-shift gather
__global__ __launch_bounds__(256) void gather_ws(const float* __restrict__ v,
                                                 const int* __restrict__ delays,
                                                 const float* __restrict__ weights,
                                                 float* __restrict__ outb) {
    const int g  = blockIdx.x * 256 + threadIdx.x;
    const int c  = g & 511;
    const int bl = g >> 9;
    const int l  = bl & 2047;
    const int b  = bl >> 11;
    const int h  = c >> 6;
    const int dh = c & 63;
    const int bh = b * 8 + h;

    const float* vb = v + (size_t)bh * 131072;
    float acc = 0.0f;
#pragma unroll
    for (int k = 0; k < KD; k++) {
        const int   d = delays[bh * KD + k];
        const float w = weights[bh * KD + k];
        const int   p = (l + d) & 2047;
        acc = fmaf(w, vb[p * 64 + dh], acc);
    }
    outb[g] = acc;
}

extern "C" void kernel_launch(void* const* d_in, const int* in_sizes, int n_in,
                              void* d_out, int out_size, void* d_ws, size_t ws_size,
                              hipStream_t stream) {
    const float* x_q  = (const float*)d_in[0];
    const float* x_kv = (const float*)d_in[1];
    const float* Wq   = (const float*)d_in[2];
    const float* bq   = (const float*)d_in[3];
    const float* Wk   = (const float*)d_in[4];
    const float* bk   = (const float*)d_in[5];
    const float* Wv   = (const float*)d_in[6];
    const float* bv   = (const float*)d_in[7];
    const float* Wo   = (const float*)d_in[8];
    const float* bo   = (const float*)d_in[9];
    float* out = (float*)d_out;

    char* ws = (char*)d_ws;
    float* qbuf  = (float*)(ws + 0);            // [B,H,DH,L]; reused as gather out
    float* kbuf  = (float*)(ws + 33554432);
    float* vbuf  = (float*)(ws + 67108864);     // [B,H,L,DH]
    float* spec  = (float*)(ws + 100663296);
    int*   dely  = (int*)  (ws + 101188096);
    float* wgt   = (float*)(ws + 101190144);

    dim3 blk(256);
    dim3 gg(DD / 128, MM / 128);   // (4, 128)

    // q, k projections (split precision) into [B,H,DH,L]
    gemm_mfma<3><<<gg, blk, 0, stream>>>(x_q,  Wq, bq, qbuf, 1);
    gemm_mfma<3><<<gg, blk, 0, stream>>>(x_kv, Wk, bk, kbuf, 1);

    hipMemsetAsync(spec, 0, 64 * 1025 * 2 * sizeof(float), stream);

    fft_fwd<<<dim3(BB * HH * DHH), blk, 0, stream>>>(qbuf, kbuf, spec);
    fft_inv_topk<<<dim3(BB * HH), blk, 0, stream>>>(spec, dely, wgt);

    // v projection (plain fp16) into [B,H,L,DH]
    gemm_mfma<1><<<gg, blk, 0, stream>>>(x_kv, Wv, bv, vbuf, 2);

    // weighted circular gather -> [B,L,D] (reuse qbuf)
    gather_ws<<<dim3(MM * DD / 256), blk, 0, stream>>>(vbuf, dely, wgt, qbuf);

    // final projection (plain fp16)
    gemm_mfma<1><<<gg, blk, 0, stream>>>(qbuf, Wo, bo, out, 0);
}